// Round 17
// baseline (18.105 us; speedup 1.0000x reference)
//
#include <hip/hip_runtime.h>
#include <hip/hip_bf16.h>
#include <math.h>

#define NB 8
#define ND 64
#define NS 512

typedef __attribute__((ext_vector_type(8))) short bf16x8;
typedef __attribute__((ext_vector_type(4))) float f32x4;
typedef __attribute__((ext_vector_type(4))) unsigned short us4;
typedef __attribute__((ext_vector_type(2))) unsigned int u32x2;
typedef __attribute__((ext_vector_type(4))) unsigned int u32x4;

__device__ __forceinline__ unsigned int pk2(float lo, float hi) {
    __hip_bfloat162 h = __float22bfloat162_rn(make_float2(lo, hi));   // v_cvt_pk_bf16_f32
    unsigned int u;
    __builtin_memcpy(&u, &h, 4);
    return u;
}
__device__ __forceinline__ unsigned short f2bf_s(float f) {
    __hip_bfloat16 h = __float2bfloat16(f);
    unsigned short u;
    __builtin_memcpy(&u, &h, 2);
    return u;
}

#define MFMA __builtin_amdgcn_mfma_f32_16x16x32_bf16

// ---------------------------------------------------------------------------
// Kernel 1 (R16 structure; MFMA-phase loops rolled too, to cut cold-I$ cost):
// self-contained part-tile compute. Block (b, v=(ti,u), ti<=u), 256 threads.
// ---------------------------------------------------------------------------
__global__ __launch_bounds__(256, 2) void k_part(const float* __restrict__ x,
                                                 const float* __restrict__ W,
                                                 float* __restrict__ part) {
    __shared__ __align__(16) unsigned short WT[128 * 64];
    __shared__ __align__(16) unsigned short xwd_i[64 * 64];
    __shared__ __align__(16) unsigned short xwd_u[64 * 64];
    __shared__ __align__(16) unsigned short xdw[64 * 64];
    __shared__ __align__(16) unsigned short alds[64 * 64];
    __shared__ __align__(16) unsigned short blds[64 * 64];
    __shared__ __align__(16) unsigned short wmb[64 * 64];
    __shared__ float na_lds[64], nb_lds[64];

    int b = blockIdx.y;
    int v = blockIdx.x;
    int u = 0;
    while ((u + 1) * (u + 2) / 2 <= v) ++u;   // w-tile
    int ti = v - u * (u + 1) / 2;             // i-tile (ti <= u)
    int i0 = ti * 64, w0 = u * 64;

    int t = threadIdx.x;
    int lane = t & 63, wv = t >> 6, c = lane & 15, g = lane >> 4, c7 = c & 7;
    int wl = t & 63, w2 = t >> 6;

    // ---- staging: x transposed tiles (rolled) ----
#pragma unroll 1
    for (int j = 0; j < 2; ++j) {
        int dblk = 2 * w2 + j;
        float vi[8], vu[8];
#pragma unroll
        for (int e = 0; e < 8; ++e) {
            const float* base = x + ((size_t)(b * ND) + 8 * dblk + e) * NS;
            vi[e] = base[i0 + wl];
            vu[e] = base[w0 + wl];
        }
        u32x4 hi, hu;
#pragma unroll
        for (int e = 0; e < 4; ++e) {
            hi[e] = pk2(vi[2 * e], vi[2 * e + 1]);
            hu[e] = pk2(vu[2 * e], vu[2 * e + 1]);
        }
        *(u32x4*)&xwd_i[wl * 64 + ((dblk ^ (wl & 7)) << 3)] = hi;
        *(u32x4*)&xwd_u[wl * 64 + ((dblk ^ (wl & 7)) << 3)] = hu;
    }
    // ---- staging: xdw [d][w] (rolled, coalesced f32x4) ----
#pragma unroll 1
    for (int q = 0; q < 2; ++q) {
        int e = t + 256 * q;
        int d = e >> 3, wc = e & 7;
        const float4* p4 = (const float4*)(x + ((size_t)(b * ND) + d) * NS + w0 + 8 * wc);
        float4 v0 = p4[0], v1 = p4[1];
        u32x4 h;
        h[0] = pk2(v0.x, v0.y); h[1] = pk2(v0.z, v0.w);
        h[2] = pk2(v1.x, v1.y); h[3] = pk2(v1.z, v1.w);
        *(u32x4*)&xdw[d * 64 + ((wc ^ (d & 7)) << 3)] = h;
    }
    // ---- staging: W -> WT (rolled) ----
    {
        int n = t & 127, half = t >> 7;
#pragma unroll 1
        for (int p = 0; p < 4; ++p) {
            int dg = half * 4 + p;
            float wv_[8];
#pragma unroll
            for (int dd = 0; dd < 8; ++dd)
                wv_[dd] = W[(size_t)(dg * 8 + dd) * ND + (n & 63) + ((n >> 6) * (ND * ND))];
            u32x4 h;
#pragma unroll
            for (int dd = 0; dd < 4; ++dd)
                h[dd] = pk2(wv_[2 * dd], wv_[2 * dd + 1]);
            *(u32x4*)&WT[n * 64 + ((dg ^ (n & 7)) << 3)] = h;
        }
    }
    __syncthreads();

    // ---- a-GEMM and b-GEMM (ks-loop rolled; acc arrays constant-indexed) ----
    {
        f32x4 aacc[4] = {{0,0,0,0},{0,0,0,0},{0,0,0,0},{0,0,0,0}};
        f32x4 bacc[4] = {{0,0,0,0},{0,0,0,0},{0,0,0,0},{0,0,0,0}};
#pragma unroll 1
        for (int ks = 0; ks < 2; ++ks) {
            int row = 16 * wv + c;
            bf16x8 Pi = *(const bf16x8*)&xwd_i[row * 64 + (((4 * ks + g) ^ c7) << 3)];
            bf16x8 Pu = *(const bf16x8*)&xwd_u[row * 64 + (((4 * ks + g) ^ c7) << 3)];
#pragma unroll
            for (int qb = 0; qb < 4; ++qb) {
                bf16x8 Qw = *(const bf16x8*)&WT[(16 * qb + c) * 64 + (((4 * ks + g) ^ c7) << 3)];
                bf16x8 Qh = *(const bf16x8*)&WT[(64 + 16 * qb + c) * 64 + (((4 * ks + g) ^ c7) << 3)];
                aacc[qb] = MFMA(Pi, Qw, aacc[qb], 0, 0, 0);
                bacc[qb] = MFMA(Pu, Qh, bacc[qb], 0, 0, 0);
            }
        }
#pragma unroll
        for (int r = 0; r < 4; ++r) {
            float sa = aacc[0][r] * aacc[0][r] + aacc[1][r] * aacc[1][r]
                     + aacc[2][r] * aacc[2][r] + aacc[3][r] * aacc[3][r];
            float sb = bacc[0][r] * bacc[0][r] + bacc[1][r] * bacc[1][r]
                     + bacc[2][r] * bacc[2][r] + bacc[3][r] * bacc[3][r];
            sa += __shfl_xor(sa, 1, 64); sa += __shfl_xor(sa, 2, 64);
            sa += __shfl_xor(sa, 4, 64); sa += __shfl_xor(sa, 8, 64);
            sb += __shfl_xor(sb, 1, 64); sb += __shfl_xor(sb, 2, 64);
            sb += __shfl_xor(sb, 4, 64); sb += __shfl_xor(sb, 8, 64);
            if (c == 0) {
                na_lds[16 * wv + 4 * g + r] = sa;
                nb_lds[16 * wv + 4 * g + r] = sb;
            }
        }
#pragma unroll
        for (int qb = 0; qb < 4; ++qb)
#pragma unroll
            for (int r = 0; r < 4; ++r) {
                int row = 16 * wv + 4 * g + r, k = 16 * qb + c;
                int off = row * 64 + (((k >> 3) ^ (row & 7)) << 3) + (k & 7);
                alds[off] = f2bf_s(aacc[qb][r]);
                blds[off] = f2bf_s(bacc[qb][r]);
            }
    }
    __syncthreads();

    // ---- GEMM1 (n-loop rolled): S[w][i] = b·a^T ; wm = masked -sqrt ----
    {
        int wrow = 16 * wv + c;
        bf16x8 P0 = *(const bf16x8*)&blds[wrow * 64 + ((g ^ c7) << 3)];
        bf16x8 P1 = *(const bf16x8*)&blds[wrow * 64 + (((4 + g) ^ c7) << 3)];
        float nbv[4];
#pragma unroll
        for (int r = 0; r < 4; ++r) nbv[r] = nb_lds[16 * wv + 4 * g + r];
        int wbase = w0 + 16 * wv + 4 * g;
#pragma unroll 1
        for (int n = 0; n < 4; ++n) {
            int arow = 16 * n + c;
            f32x4 a1 = {0.f, 0.f, 0.f, 0.f};
            bf16x8 Q0 = *(const bf16x8*)&alds[arow * 64 + ((g ^ c7) << 3)];
            bf16x8 Q1 = *(const bf16x8*)&alds[arow * 64 + (((4 + g) ^ c7) << 3)];
            a1 = MFMA(P0, Q0, a1, 0, 0, 0);
            a1 = MFMA(P1, Q1, a1, 0, 0, 0);
            float navv = na_lds[arow];
            int i_glob = i0 + arow;
            float vals[4];
#pragma unroll
            for (int r = 0; r < 4; ++r) {
                float s2v = navv + nbv[r] + 2.f * a1[r];
                vals[r] = (i_glob <= wbase + r) ? -sqrtf(fmaxf(s2v, 0.f)) : 0.f;
            }
            u32x2 pk;
            pk[0] = pk2(vals[0], vals[1]);
            pk[1] = pk2(vals[2], vals[3]);
            int wblk = 2 * wv + (g >> 1);
            *(u32x2*)&wmb[arow * 64 + ((wblk ^ (arow & 7)) << 3) + 4 * (g & 1)] = pk;
        }
    }
    __syncthreads();

    // ---- GEMM2 (nd-loop rolled): part = wm·x^T, disjoint stores ----
    {
        int il = 16 * wv + c;
        bf16x8 a20 = *(const bf16x8*)&wmb[il * 64 + ((g ^ c7) << 3)];
        bf16x8 a21 = *(const bf16x8*)&wmb[il * 64 + (((4 + g) ^ c7) << 3)];
#pragma unroll 1
        for (int nd = 0; nd < 4; ++nd) {
            int d = 16 * nd + c;
            bf16x8 q0 = *(const bf16x8*)&xdw[d * 64 + ((g ^ c7) << 3)];
            bf16x8 q1 = *(const bf16x8*)&xdw[d * 64 + (((4 + g) ^ c7) << 3)];
            f32x4 acc = {0.f, 0.f, 0.f, 0.f};
            acc = MFMA(a20, q0, acc, 0, 0, 0);
            acc = MFMA(a21, q1, acc, 0, 0, 0);
            float* pp = part + (((size_t)u * NB + b) * ND + d) * NS + i0 + 16 * wv + 4 * g;
            *(f32x4*)pp = acc;
        }
    }
}

// ---------------------------------------------------------------------------
// Kernel 2 (R11-validated): out = rowsum(x) + sum part slices.
// 512 blocks x 128 threads, all-f32x4.
// ---------------------------------------------------------------------------
__global__ __launch_bounds__(128) void k_red(const float* __restrict__ x,
                                             const float* __restrict__ part,
                                             float* __restrict__ out) {
    __shared__ float red[2];
    int b = blockIdx.y, d = blockIdx.x, t = threadIdx.x;   // t < 128
    const float* xr = x + ((size_t)b * ND + d) * NS;

    float4 xv = *(const float4*)(xr + 4 * t);
    float s = xv.x + xv.y + xv.z + xv.w;
#pragma unroll
    for (int m = 32; m >= 1; m >>= 1) s += __shfl_xor(s, m, 64);
    if ((t & 63) == 0) red[t >> 6] = s;
    __syncthreads();
    float rs = red[0] + red[1];

    int it = t >> 4;
    f32x4 vv = {rs, rs, rs, rs};
#pragma unroll
    for (int u = 0; u < 8; ++u) {
        if (u >= it) {
            f32x4 pv = *(const f32x4*)&part[(((size_t)u * NB + b) * ND + d) * NS + 4 * t];
            vv[0] += pv[0]; vv[1] += pv[1]; vv[2] += pv[2]; vv[3] += pv[3];
        }
    }
    *(f32x4*)&out[((size_t)b * ND + d) * NS + 4 * t] = vv;
}

extern "C" void kernel_launch(void* const* d_in, const int* in_sizes, int n_in,
                              void* d_out, int out_size, void* d_ws, size_t ws_size,
                              hipStream_t stream) {
    const float* x = (const float*)d_in[0];
    const float* W = (const float*)d_in[1];
    float* out  = (float*)d_out;
    float* part = (float*)d_ws;                 // 8 MB

    k_part<<<dim3(36, NB), dim3(256), 0, stream>>>(x, W, part);
    k_red <<<dim3(ND, NB), dim3(128), 0, stream>>>(x, part, out);
}